// Round 1
// baseline (2420.698 us; speedup 1.0000x reference)
//
#include <hip/hip_runtime.h>
#include <hip/hip_bf16.h>
#include <math.h>

#define DIM 1280
#define NHEADS 16
#define HD 80
#define NSEG 8
#define SEGLEN 1024
#define TOTAL (NSEG*SEGLEN)   // 8192

// ---------------------------------------------------------------------------
// Tiled fp32 GEMM: C = A(MxK) @ B(KxN) + bias.  64x64 tile, BK=16, 256 thr,
// 4x4 micro-tile per thread.  MODE 0: plain row-major C. MODE 1: scatter into
// q/k/v buffers laid out [seg][head][pos][dim].
// ---------------------------------------------------------------------------
template<int MODE>
__global__ __launch_bounds__(256) void gemm_f32(
    const float* __restrict__ A, const float* __restrict__ B,
    const float* __restrict__ bias,
    float* __restrict__ C0, float* __restrict__ C1, float* __restrict__ C2,
    int M, int N, int K)
{
    // As padded to 68 (writes (4c+r)%32 distinct -> <=2-way; reads 16B aligned)
    __shared__ __align__(16) float As[16][68];
    __shared__ __align__(16) float Bs[16][64];
    const int tid = threadIdx.x;
    const int ty = tid >> 4;      // 0..15
    const int tx = tid & 15;      // 0..15
    const int brow = blockIdx.y * 64;
    const int bcol = blockIdx.x * 64;

    float acc[4][4] = {{0.f,0.f,0.f,0.f},{0.f,0.f,0.f,0.f},
                       {0.f,0.f,0.f,0.f},{0.f,0.f,0.f,0.f}};

    for (int k0 = 0; k0 < K; k0 += 16) {
        // A tile: 64 rows x 16 k.  Stored transposed As[k][row].
        #pragma unroll
        for (int p = 0; p < 4; ++p) {
            int r = p*16 + (tid >> 4);
            int c = tid & 15;
            As[c][r] = A[(size_t)(brow + r)*K + k0 + c];
        }
        // B tile: 16 k x 64 cols.
        #pragma unroll
        for (int p = 0; p < 4; ++p) {
            int r = p*4 + (tid >> 6);
            int c = tid & 63;
            Bs[r][c] = B[(size_t)(k0 + r)*N + bcol + c];
        }
        __syncthreads();
        #pragma unroll
        for (int kk = 0; kk < 16; ++kk) {
            const float4 a4 = *(const float4*)&As[kk][4*ty];
            const float4 b4 = *(const float4*)&Bs[kk][4*tx];
            const float av[4] = {a4.x, a4.y, a4.z, a4.w};
            const float bv[4] = {b4.x, b4.y, b4.z, b4.w};
            #pragma unroll
            for (int i = 0; i < 4; ++i)
                #pragma unroll
                for (int j = 0; j < 4; ++j)
                    acc[i][j] = fmaf(av[i], bv[j], acc[i][j]);
        }
        __syncthreads();
    }

    #pragma unroll
    for (int i = 0; i < 4; ++i) {
        const int r = brow + 4*ty + i;
        #pragma unroll
        for (int j = 0; j < 4; ++j) {
            const int c = bcol + 4*tx + j;
            float val = acc[i][j] + bias[c];
            if (MODE == 0) {
                C0[(size_t)r*N + c] = val;
            } else {
                int part = c / DIM;           // 0,1,2 -> q,k,v
                int rem  = c - part*DIM;
                int hh = rem / HD;
                int dd = rem - hh*HD;
                int g  = r >> 10;             // seg
                int ll = r & 1023;            // pos in seg
                float* dst = (part == 0) ? C0 : (part == 1 ? C1 : C2);
                dst[((size_t)((g*NHEADS + hh)*SEGLEN + ll))*HD + dd] = val;
            }
        }
    }
}

// ---------------------------------------------------------------------------
// RoPE applied in-place to q and k buffers ([seg][head][pos][dim]).
// One thread per (g,h,l,d<40) pair; handles both halves, both q and k.
// ---------------------------------------------------------------------------
__global__ __launch_bounds__(256) void rope_f32(
    float* __restrict__ qb, float* __restrict__ kb,
    const float* __restrict__ rp)
{
    int idx = blockIdx.x * 256 + threadIdx.x;  // 8*16*1024*40 total
    int d  = idx % 40;
    int t  = idx / 40;
    int l  = t & 1023;
    int t2 = t >> 10;
    int h  = t2 & 15;
    int g  = t2 >> 4;
    int s  = (g << 10) + l;                    // global token
    float ang = rp[s*40 + d];
    float si, co;
    sincosf(ang, &si, &co);
    size_t base = ((size_t)((g*NHEADS + h)*SEGLEN + l))*HD;
    float q0 = qb[base + d], q1 = qb[base + d + 40];
    qb[base + d]      = q0*co - q1*si;
    qb[base + d + 40] = q1*co + q0*si;
    float k0 = kb[base + d], k1 = kb[base + d + 40];
    kb[base + d]      = k0*co - k1*si;
    kb[base + d + 40] = k1*co + k0*si;
}

// ---------------------------------------------------------------------------
// Flash attention, fp32, per (seg, head, 64-row Q tile). 256 threads.
// Thread (ty,tx) (16x16 grid): scores 4x4 (rows 4ty+i, kcols 4tx+j),
// output 4 rows x 5 dcols (d = 5tx..5tx+4).  LDS rows padded to 81 floats
// (all read patterns <=2-way bank aliasing = free on wave64/32-bank).
// ---------------------------------------------------------------------------
__global__ __launch_bounds__(256) void attn_f32(
    const float* __restrict__ qb, const float* __restrict__ kb,
    const float* __restrict__ vb, float* __restrict__ ob)
{
    const int qt = blockIdx.x;   // 0..15
    const int h  = blockIdx.y;   // 0..15
    const int g  = blockIdx.z;   // 0..7
    const float scale = 0.11180339887498949f;  // 1/sqrt(80)

    __shared__ float sQ[64][81];
    __shared__ float sK[64][81];
    __shared__ float sV[64][81];
    __shared__ float sP[64][65];

    const int tid = threadIdx.x;
    const int ty = tid >> 4;
    const int tx = tid & 15;

    const float* Qg = qb + ((size_t)((g*NHEADS + h)*SEGLEN + qt*64))*HD;
    const float* Kg = kb + ((size_t)((g*NHEADS + h)*SEGLEN))*HD;
    const float* Vg = vb + ((size_t)((g*NHEADS + h)*SEGLEN))*HD;

    // Load Q tile (scaled).
    #pragma unroll
    for (int p = 0; p < 5; ++p) {
        int idx = p*256 + tid;        // 0..1279 float4s
        int r = idx / 20, c4 = idx % 20;
        float4 v = *(const float4*)(Qg + r*HD + c4*4);
        sQ[r][c4*4+0] = v.x*scale; sQ[r][c4*4+1] = v.y*scale;
        sQ[r][c4*4+2] = v.z*scale; sQ[r][c4*4+3] = v.w*scale;
    }

    float m[4]  = {-3.0e38f,-3.0e38f,-3.0e38f,-3.0e38f};
    float lse[4] = {0.f,0.f,0.f,0.f};
    float O[4][5] = {};

    for (int kt = 0; kt < 16; ++kt) {
        // Load K/V tiles
        #pragma unroll
        for (int p = 0; p < 5; ++p) {
            int idx = p*256 + tid;
            int r = idx / 20, c4 = idx % 20;
            float4 kv = *(const float4*)(Kg + (size_t)(kt*64 + r)*HD + c4*4);
            sK[r][c4*4+0] = kv.x; sK[r][c4*4+1] = kv.y;
            sK[r][c4*4+2] = kv.z; sK[r][c4*4+3] = kv.w;
            float4 vv = *(const float4*)(Vg + (size_t)(kt*64 + r)*HD + c4*4);
            sV[r][c4*4+0] = vv.x; sV[r][c4*4+1] = vv.y;
            sV[r][c4*4+2] = vv.z; sV[r][c4*4+3] = vv.w;
        }
        __syncthreads();

        // Scores 4x4
        float sc[4][4] = {};
        for (int d = 0; d < 80; ++d) {
            float a[4], b[4];
            #pragma unroll
            for (int i = 0; i < 4; ++i) a[i] = sQ[4*ty+i][d];
            #pragma unroll
            for (int j = 0; j < 4; ++j) b[j] = sK[4*tx+j][d];
            #pragma unroll
            for (int i = 0; i < 4; ++i)
                #pragma unroll
                for (int j = 0; j < 4; ++j)
                    sc[i][j] = fmaf(a[i], b[j], sc[i][j]);
        }

        // Online softmax update (row groups of 16 tx-lanes within a wave)
        #pragma unroll
        for (int i = 0; i < 4; ++i) {
            float rm = fmaxf(fmaxf(sc[i][0], sc[i][1]), fmaxf(sc[i][2], sc[i][3]));
            #pragma unroll
            for (int off = 1; off < 16; off <<= 1)
                rm = fmaxf(rm, __shfl_xor(rm, off, 64));
            float mnew = fmaxf(m[i], rm);
            float alpha = expf(m[i] - mnew);
            float psum = 0.f;
            #pragma unroll
            for (int j = 0; j < 4; ++j) {
                float p = expf(sc[i][j] - mnew);
                sP[4*ty+i][4*tx+j] = p;
                psum += p;
            }
            #pragma unroll
            for (int off = 1; off < 16; off <<= 1)
                psum += __shfl_xor(psum, off, 64);
            lse[i] = lse[i]*alpha + psum;
            m[i] = mnew;
            #pragma unroll
            for (int j = 0; j < 5; ++j) O[i][j] *= alpha;
        }
        __syncthreads();  // sP fully written, sV ready

        // PV accumulate
        for (int kc = 0; kc < 64; ++kc) {
            float vv[5];
            #pragma unroll
            for (int j = 0; j < 5; ++j) vv[j] = sV[kc][tx*5 + j];
            #pragma unroll
            for (int i = 0; i < 4; ++i) {
                float p = sP[4*ty+i][kc];
                #pragma unroll
                for (int j = 0; j < 5; ++j)
                    O[i][j] = fmaf(p, vv[j], O[i][j]);
            }
        }
        __syncthreads();  // protect sK/sV/sP before next tile's loads
    }

    // Normalize and write out in token-major [s][h*80+d] layout for proj GEMM.
    #pragma unroll
    for (int i = 0; i < 4; ++i) {
        float inv = 1.f / lse[i];
        int srow = g*SEGLEN + qt*64 + 4*ty + i;
        size_t base = (size_t)srow*DIM + h*HD + tx*5;
        #pragma unroll
        for (int j = 0; j < 5; ++j) ob[base + j] = O[i][j]*inv;
    }
}

// ---------------------------------------------------------------------------
extern "C" void kernel_launch(void* const* d_in, const int* in_sizes, int n_in,
                              void* d_out, int out_size, void* d_ws, size_t ws_size,
                              hipStream_t stream) {
    const float* hs     = (const float*)d_in[0];   // 8192 x 1280
    const float* rope   = (const float*)d_in[1];   // 8192 x 40
    const float* qkv_w  = (const float*)d_in[2];   // 1280 x 3840
    const float* qkv_b  = (const float*)d_in[3];   // 3840
    const float* proj_w = (const float*)d_in[4];   // 1280 x 1280
    const float* proj_b = (const float*)d_in[5];   // 1280
    // d_in[6] = cu_seqlens (fixed 1024-token segments; unused)

    float* ws = (float*)d_ws;
    const size_t elems = (size_t)TOTAL * DIM;      // 10,485,760
    float* qb = ws;
    float* kb = ws + elems;
    float* vb = ws + 2*elems;
    float* ob = ws + 3*elems;

    // 1. QKV GEMM + bias, scatter to q/k/v [seg][head][pos][dim]
    gemm_f32<1><<<dim3(3*DIM/64, TOTAL/64), 256, 0, stream>>>(
        hs, qkv_w, qkv_b, qb, kb, vb, TOTAL, 3*DIM, DIM);

    // 2. RoPE in-place on q,k
    int rope_threads = NSEG*NHEADS*SEGLEN*(HD/2);  // 5,242,880
    rope_f32<<<rope_threads/256, 256, 0, stream>>>(qb, kb, rope);

    // 3. Flash attention -> ob (token-major 8192x1280)
    attn_f32<<<dim3(SEGLEN/64, NHEADS, NSEG), 256, 0, stream>>>(qb, kb, vb, ob);

    // 4. Output projection
    gemm_f32<0><<<dim3(DIM/64, TOTAL/64), 256, 0, stream>>>(
        ob, proj_w, proj_b, (float*)d_out, nullptr, nullptr, TOTAL, DIM, DIM);
}

// Round 2
// 441.550 us; speedup vs baseline: 5.4823x; 5.4823x over previous
//
#include <hip/hip_runtime.h>
#include <hip/hip_bf16.h>
#include <math.h>

#define DIM 1280
#define NHEADS 16
#define HD 80
#define HDP 96            // head dim padded to 3*32 for MFMA k-steps
#define NSEG 8
#define SEGLEN 1024
#define TOTAL (NSEG*SEGLEN)   // 8192

typedef unsigned short u16;
typedef __attribute__((ext_vector_type(8))) short bf16x8;
typedef __attribute__((ext_vector_type(4))) float f32x4;

__device__ __forceinline__ u16 f2b(float f) {
    union { float f; unsigned int i; } v; v.f = f;
    unsigned int x = v.i;
    unsigned int r = x + 0x7FFFu + ((x >> 16) & 1u);   // RNE
    return (u16)(r >> 16);
}
__device__ __forceinline__ float b2f(u16 u) {
    union { unsigned int i; float f; } v; v.i = ((unsigned int)u) << 16;
    return v.f;
}
__device__ __forceinline__ void gload16(const u16* g, u16* l) {
    __builtin_amdgcn_global_load_lds(
        (const __attribute__((address_space(1))) unsigned int*)g,
        (__attribute__((address_space(3))) unsigned int*)l, 16, 0, 0);
}

// ---------------------------------------------------------------------------
// fp32 -> bf16 elementwise convert (4 per thread)
// ---------------------------------------------------------------------------
__global__ __launch_bounds__(256) void cvt_f32_bf16(const float* __restrict__ in,
                                                    u16* __restrict__ out, int n4) {
    int i = blockIdx.x * 256 + threadIdx.x;
    if (i >= n4) return;
    float4 a = ((const float4*)in)[i];
    u16 o[4] = { f2b(a.x), f2b(a.y), f2b(a.z), f2b(a.w) };
    *(ulong1*)&out[i*4] = *(ulong1*)o;
}

// ---------------------------------------------------------------------------
// Transpose + convert weights: in [K][N] fp32 -> out [N][K] bf16 (B^T layout)
// ---------------------------------------------------------------------------
__global__ __launch_bounds__(256) void cvtT_w(const float* __restrict__ in,
                                              u16* __restrict__ out, int K, int N) {
    __shared__ float t[32][33];
    const int kb = blockIdx.x * 32, nb = blockIdx.y * 32;
    const int tx = threadIdx.x & 31, ty = threadIdx.x >> 5;   // 8 rows per pass
    #pragma unroll
    for (int i = 0; i < 4; ++i) {
        int r = i*8 + ty;
        t[r][tx] = in[(size_t)(kb + r)*N + nb + tx];
    }
    __syncthreads();
    #pragma unroll
    for (int i = 0; i < 4; ++i) {
        int n = i*8 + ty;
        out[(size_t)(nb + n)*K + kb + tx] = f2b(t[tx][n]);
    }
}

// ---------------------------------------------------------------------------
// m97-style bf16 MFMA GEMM: C = A(MxK) @ BT(NxK)^T + bias.
// 128x128 tile, BK=32, 256 thr = 4 waves, each wave a 64x64 quadrant.
// MODE 0: fp32 row-major C.  MODE 1: bf16 scatter into q/k ([g][h][l][96],
// pads untouched) and v ([g][h][l][80]).
// ---------------------------------------------------------------------------
template<int MODE>
__global__ __launch_bounds__(256) void gemm_bf16(
    const u16* __restrict__ A, const u16* __restrict__ BT,
    const float* __restrict__ bias,
    float* __restrict__ Cf, u16* __restrict__ qo, u16* __restrict__ ko,
    u16* __restrict__ vo, int M, int N, int K)
{
    __shared__ u16 sA[128*32];
    __shared__ u16 sB[128*32];
    const int tid = threadIdx.x;
    const int w = tid >> 6, l = tid & 63;
    const int lq = l & 15, lg = l >> 4;
    const int brow = blockIdx.y * 128, bcol = blockIdx.x * 128;
    const int wr = (w >> 1) * 64, wc = (w & 1) * 64;
    const int arow = w*32 + (l >> 2);      // staging row (+16 for i=1)
    const int acol = (l & 3) * 8;          // staging k-offset

    f32x4 acc[4][4] = {};

    for (int k0 = 0; k0 < K; k0 += 32) {
        __syncthreads();
        #pragma unroll
        for (int i = 0; i < 2; ++i) {
            gload16(A  + (size_t)(brow + arow + i*16)*K + k0 + acol, &sA[w*1024 + i*512]);
            gload16(BT + (size_t)(bcol + arow + i*16)*K + k0 + acol, &sB[w*1024 + i*512]);
        }
        __syncthreads();
        bf16x8 af[4], bfr[4];
        #pragma unroll
        for (int m = 0; m < 4; ++m) af[m]  = *(const bf16x8*)&sA[(wr + m*16 + lq)*32 + lg*8];
        #pragma unroll
        for (int n = 0; n < 4; ++n) bfr[n] = *(const bf16x8*)&sB[(wc + n*16 + lq)*32 + lg*8];
        #pragma unroll
        for (int m = 0; m < 4; ++m)
            #pragma unroll
            for (int n = 0; n < 4; ++n)
                acc[m][n] = __builtin_amdgcn_mfma_f32_16x16x32_bf16(af[m], bfr[n], acc[m][n], 0, 0, 0);
    }

    #pragma unroll
    for (int m = 0; m < 4; ++m) {
        #pragma unroll
        for (int n = 0; n < 4; ++n) {
            #pragma unroll
            for (int r = 0; r < 4; ++r) {
                const int row = brow + wr + m*16 + lg*4 + r;   // C/D: row=(l>>4)*4+reg
                const int col = bcol + wc + n*16 + lq;         //      col=l&15
                float val = acc[m][n][r] + bias[col];
                if (MODE == 0) {
                    Cf[(size_t)row*N + col] = val;
                } else {
                    int part = col / DIM, rem = col - part*DIM;
                    int hh = rem / HD, dd = rem - hh*HD;
                    int g = row >> 10, ll = row & 1023;
                    size_t tok = (size_t)((g*NHEADS + hh)*SEGLEN + ll);
                    if      (part == 0) qo[tok*HDP + dd] = f2b(val);
                    else if (part == 1) ko[tok*HDP + dd] = f2b(val);
                    else                vo[tok*HD  + dd] = f2b(val);
                }
            }
        }
    }
}

// ---------------------------------------------------------------------------
// RoPE in-place on bf16 q,k (layout [g][h][l][96]); also zero-fills pads 80..95.
// 48 threads per (g,h,l): d<40 -> rope pair, d>=40 -> two pad zeros each.
// ---------------------------------------------------------------------------
__global__ __launch_bounds__(256) void rope_pad(u16* __restrict__ qb, u16* __restrict__ kb,
                                                const float* __restrict__ rp)
{
    int idx = blockIdx.x * 256 + threadIdx.x;
    int d = idx % 48;
    int t = idx / 48;
    int l = t & 1023, h = (t >> 10) & 15, g = t >> 14;
    size_t base = ((size_t)((g*NHEADS + h)*SEGLEN + l)) * HDP;
    if (d < 40) {
        float ang = rp[(size_t)(g*SEGLEN + l)*40 + d];
        float si, co;
        sincosf(ang, &si, &co);
        float q0 = b2f(qb[base + d]), q1 = b2f(qb[base + d + 40]);
        qb[base + d]      = f2b(q0*co - q1*si);
        qb[base + d + 40] = f2b(q1*co + q0*si);
        float k0 = b2f(kb[base + d]), k1 = b2f(kb[base + d + 40]);
        kb[base + d]      = f2b(k0*co - k1*si);
        kb[base + d + 40] = f2b(k1*co + k0*si);
    } else {
        int dz = d - 40;
        qb[base + 80 + dz] = 0; qb[base + 88 + dz] = 0;
        kb[base + 80 + dz] = 0; kb[base + 88 + dz] = 0;
    }
}

// ---------------------------------------------------------------------------
// V transpose per head: v [gh][1024][80] -> vt [gh][80][1024]  (bf16)
// ---------------------------------------------------------------------------
__global__ __launch_bounds__(256) void transpose_v(const u16* __restrict__ v,
                                                   u16* __restrict__ vt)
{
    __shared__ u16 sT[64][82];
    const int gh = blockIdx.y;       // 0..127
    const int st = blockIdx.x;       // 0..15 seq tile
    const u16* src = v  + (size_t)gh*SEGLEN*HD + (size_t)st*64*HD;
    u16*       dst = vt + (size_t)gh*HD*SEGLEN + (size_t)st*64;
    const int tid = threadIdx.x;
    #pragma unroll
    for (int p = 0; p < 20; ++p) {
        int e = p*256 + tid;
        int r = e / 80, c = e - r*80;
        sT[r][c] = src[r*HD + c];
    }
    __syncthreads();
    #pragma unroll
    for (int p = 0; p < 20; ++p) {
        int e = p*256 + tid;
        int dd = e >> 6, s = e & 63;
        dst[(size_t)dd*SEGLEN + s] = sT[s][dd];
    }
}

// ---------------------------------------------------------------------------
// Flash attention, bf16 MFMA, fp32 online softmax.
// Block = (qt, h, g), 256 thr = 4 waves; wave w owns q rows [w*16, w*16+16).
// Swapped QK^T: mfma(A=K, B=Q) -> S^T; lane l holds S[q = w*16 + (l&15)][k]
// for 16 k-values -> in-wave softmax; P via per-wave padded LDS -> A-frags;
// PV: mfma(A=P, B=V) with V B-frags from transposed-V LDS tile.
// ---------------------------------------------------------------------------
__global__ __launch_bounds__(256) void attn_mfma(
    const u16* __restrict__ qb, const u16* __restrict__ kb,
    const u16* __restrict__ vt, u16* __restrict__ ob)
{
    const int qt = blockIdx.x;   // 0..15
    const int h  = blockIdx.y;   // 0..15
    const int g  = blockIdx.z;   // 0..7
    const float scale = 0.11180339887498949f;   // 1/sqrt(80)
    const float L2E = 1.4426950408889634f;

    __shared__ u16 sK[64*HDP];        // [64 krow][96 kd] linear (global_load_lds)
    __shared__ u16 sVT[80][72];       // [d][64 seq] +8 pad
    __shared__ u16 sP[4][16][72];     // per-wave P: [16 q][64 k] +8 pad

    const int tid = threadIdx.x;
    const int w = tid >> 6, l = tid & 63;
    const int lq = l & 15, lg = l >> 4;

    const size_t gh = (size_t)(g*NHEADS + h);
    const u16* Qg  = qb + gh*SEGLEN*HDP + (size_t)qt*64*HDP;
    const u16* Kg  = kb + gh*SEGLEN*HDP;
    const u16* VTg = vt + gh*HD*SEGLEN;

    // Q B-fragments for this wave's 16 q-rows: col=q=(l&15), k=(l>>4)*8+j
    bf16x8 qf[3];
    #pragma unroll
    for (int s = 0; s < 3; ++s)
        qf[s] = *(const bf16x8*)(Qg + (size_t)(w*16 + lq)*HDP + s*32 + lg*8);

    float m = -1e30f, lse = 0.f;      // per q=w*16+lq (replicated over lg)
    f32x4 Oc[5] = {};                 // O C-frags: row q'=lg*4+r, col d=n*16+lq

    for (int kt = 0; kt < 16; ++kt) {
        __syncthreads();
        // stage K tile: 64x96 bf16 = 12288 B = 12 chunks of 1024; wave w: chunks i*4+w
        #pragma unroll
        for (int i = 0; i < 3; ++i) {
            int o = (i*4 + w)*1024 + l*16;          // byte offset in sK
            int row = o / 192, cc = (o % 192) >> 1;
            gload16(Kg + (size_t)(kt*64 + row)*HDP + cc, &sK[(i*4 + w)*512]);
        }
        // stage V^T tile (reg-staged, padded LDS): 80 x 64
        #pragma unroll
        for (int p = 0; p < 3; ++p) {
            int c = p*256 + tid;
            if (c < 640) {
                int dd = c >> 3, s8 = (c & 7)*8;
                *(bf16x8*)&sVT[dd][s8] =
                    *(const bf16x8*)(VTg + (size_t)dd*SEGLEN + kt*64 + s8);
            }
        }
        __syncthreads();

        // QK^T (swapped): 4 k-frags x 3 kd-steps
        f32x4 sf[4];
        #pragma unroll
        for (int fi = 0; fi < 4; ++fi) {
            f32x4 c = {0.f, 0.f, 0.f, 0.f};
            #pragma unroll
            for (int s = 0; s < 3; ++s) {
                bf16x8 a = *(const bf16x8*)&sK[(fi*16 + lq)*HDP + s*32 + lg*8];
                c = __builtin_amdgcn_mfma_f32_16x16x32_bf16(a, qf[s], c, 0, 0, 0);
            }
            sf[fi] = c;
        }

        // online softmax for q = w*16+lq; lane holds k = fi*16 + lg*4 + r
        float sv[4][4];
        float rm = -1e30f;
        #pragma unroll
        for (int fi = 0; fi < 4; ++fi)
            #pragma unroll
            for (int r = 0; r < 4; ++r) {
                float x = sf[fi][r] * scale;
                sv[fi][r] = x;
                rm = fmaxf(rm, x);
            }
        rm = fmaxf(rm, __shfl_xor(rm, 16, 64));
        rm = fmaxf(rm, __shfl_xor(rm, 32, 64));
        float mnew = fmaxf(m, rm);
        float alpha = exp2f((m - mnew) * L2E);
        float psum = 0.f;
        #pragma unroll
        for (int fi = 0; fi < 4; ++fi)
            #pragma unroll
            for (int r = 0; r < 4; ++r) {
                float p = exp2f((sv[fi][r] - mnew) * L2E);
                sv[fi][r] = p;
                psum += p;
            }
        psum += __shfl_xor(psum, 16, 64);
        psum += __shfl_xor(psum, 32, 64);
        lse = lse * alpha + psum;
        m = mnew;

        // write P (bf16) to per-wave LDS: sP[w][q][k], 4 consecutive k per frag
        #pragma unroll
        for (int fi = 0; fi < 4; ++fi) {
            unsigned int w0 = (unsigned int)f2b(sv[fi][0]) | ((unsigned int)f2b(sv[fi][1]) << 16);
            unsigned int w1 = (unsigned int)f2b(sv[fi][2]) | ((unsigned int)f2b(sv[fi][3]) << 16);
            uint2 val; val.x = w0; val.y = w1;
            *(uint2*)&sP[w][lq][fi*16 + lg*4] = val;
        }

        // rescale O by alpha (per O-row q' = lg*4 + r)
        float a0 = __shfl(alpha, lg*4 + 0, 64);
        float a1 = __shfl(alpha, lg*4 + 1, 64);
        float a2 = __shfl(alpha, lg*4 + 2, 64);
        float a3 = __shfl(alpha, lg*4 + 3, 64);
        #pragma unroll
        for (int n = 0; n < 5; ++n) {
            Oc[n][0] *= a0; Oc[n][1] *= a1; Oc[n][2] *= a2; Oc[n][3] *= a3;
        }

        // PV: A = P (row=q=l&15, k=lg*8+j), B = V (k=seq, col=d=n*16+lq)
        #pragma unroll
        for (int ks = 0; ks < 2; ++ks) {
            bf16x8 pa = *(const bf16x8*)&sP[w][lq][ks*32 + lg*8];
            #pragma unroll
            for (int n = 0; n < 5; ++n) {
                bf16x8 vb = *(const bf16x8*)&sVT[n*16 + lq][ks*32 + lg*8];
                Oc[n] = __builtin_amdgcn_mfma_f32_16x16x32_bf16(pa, vb, Oc[n], 0, 0, 0);
            }
        }
    }

    // normalize + write out token-major bf16 [8192][1280]
    float inv = 1.f / lse;
    float i0 = __shfl(inv, lg*4 + 0, 64);
    float i1 = __shfl(inv, lg*4 + 1, 64);
    float i2 = __shfl(inv, lg*4 + 2, 64);
    float i3 = __shfl(inv, lg*4 + 3, 64);
    const float iv[4] = { i0, i1, i2, i3 };
    #pragma unroll
    for (int n = 0; n < 5; ++n) {
        #pragma unroll
        for (int r = 0; r < 4; ++r) {
            int tok = g*SEGLEN + qt*64 + w*16 + lg*4 + r;
            int col = h*HD + n*16 + lq;
            ob[(size_t)tok*DIM + col] = f2b(Oc[n][r] * iv[r]);
        }
    }
}

// ---------------------------------------------------------------------------
extern "C" void kernel_launch(void* const* d_in, const int* in_sizes, int n_in,
                              void* d_out, int out_size, void* d_ws, size_t ws_size,
                              hipStream_t stream) {
    const float* hs     = (const float*)d_in[0];   // 8192 x 1280
    const float* rope   = (const float*)d_in[1];   // 8192 x 40
    const float* qkv_w  = (const float*)d_in[2];   // 1280 x 3840
    const float* qkv_b  = (const float*)d_in[3];   // 3840
    const float* proj_w = (const float*)d_in[4];   // 1280 x 1280
    const float* proj_b = (const float*)d_in[5];   // 1280
    // d_in[6] = cu_seqlens (fixed 1024-token segments)

    char* ws = (char*)d_ws;
    u16* hsb    = (u16*)(ws);                          // 8192x1280       (20,971,520 B)
    u16* wqkvt  = (u16*)(ws + 20971520);               // 3840x1280       ( 9,830,400 B)
    u16* wprojt = (u16*)(ws + 30801920);               // 1280x1280       ( 3,276,800 B)
    u16* qpad   = (u16*)(ws + 34078720);               // 128x1024x96     (25,165,824 B)
    u16* kpad   = (u16*)(ws + 59244544);               // 128x1024x96     (25,165,824 B)
    u16* vbuf   = (u16*)(ws + 84410368);               // 128x1024x80     (20,971,520 B)
    u16* vtb    = (u16*)(ws + 105381888);              // 128x80x1024     (20,971,520 B)
    u16* obb    = (u16*)(ws + 126353408);              // 8192x1280       (20,971,520 B)

    // 1. converts
    cvt_f32_bf16<<<(TOTAL*DIM/4 + 255)/256, 256, 0, stream>>>(hs, hsb, TOTAL*DIM/4);
    cvtT_w<<<dim3(DIM/32, 3*DIM/32), 256, 0, stream>>>(qkv_w, wqkvt, DIM, 3*DIM);
    cvtT_w<<<dim3(DIM/32, DIM/32), 256, 0, stream>>>(proj_w, wprojt, DIM, DIM);

    // 2. QKV GEMM (bf16 MFMA) + scatter
    gemm_bf16<1><<<dim3(3*DIM/128, TOTAL/128), 256, 0, stream>>>(
        hsb, wqkvt, qkv_b, nullptr, qpad, kpad, vbuf, TOTAL, 3*DIM, DIM);

    // 3. RoPE + pad zero-fill
    rope_pad<<<NSEG*NHEADS*SEGLEN*48/256, 256, 0, stream>>>(qpad, kpad, rope);

    // 4. V transpose
    transpose_v<<<dim3(SEGLEN/64, NSEG*NHEADS), 256, 0, stream>>>(vbuf, vtb);

    // 5. flash attention
    attn_mfma<<<dim3(SEGLEN/64, NHEADS, NSEG), 256, 0, stream>>>(qpad, kpad, vtb, obb);

    // 6. output projection (fp32 out)
    gemm_bf16<0><<<dim3(DIM/128, TOTAL/128), 256, 0, stream>>>(
        obb, wprojt, proj_b, (float*)d_out, nullptr, nullptr, nullptr, TOTAL, DIM, DIM);
}